// Round 9
// baseline (175.358 us; speedup 1.0000x reference)
//
#include <hip/hip_runtime.h>

typedef unsigned long long u64;
typedef int i32x4 __attribute__((ext_vector_type(4)));

#define HW    3136      // 56*56 ; 3136 % 64 == 0 -> tiles never straddle images
#define CIN   256
#define CMID  768
#define EPSV  1e-5

__device__ __forceinline__ u64 shfl_xor64(u64 v, int m) {
  unsigned lo = (unsigned)__shfl_xor((int)(unsigned)v, m);
  unsigned hi = (unsigned)__shfl_xor((int)(v >> 32), m);
  return ((u64)hi << 32) | lo;
}

// 16 sign bits -> 16 i8 bytes (bit=1 -> 0xFF(-1), bit=0 -> 0x01(+1))
__device__ __forceinline__ i32x4 unpack16(unsigned bits) {
  i32x4 r;
  #pragma unroll
  for (int q = 0; q < 4; ++q) {
    unsigned nib    = (bits >> (4 * q)) & 0xFu;
    unsigned spread = (nib * 0x00204081u) & 0x01010101u;   // bit i -> byte i LSB
    unsigned d      = 0x01010101u ^ ((spread << 8) - (spread << 1)); // ^= 0xFE per set byte
    r[q] = (int)d;
  }
  return r;
}

// ---------------------------------------------------------------------------
// prep: weights -> i8 sign matrices (-1/0/+1); BN folded to (inv, c) f32 pairs
// ---------------------------------------------------------------------------
__global__ __launch_bounds__(64) void prep_kernel(
    const float* __restrict__ w1, const float* __restrict__ w2,
    const float* __restrict__ g1, const float* __restrict__ b1,
    const float* __restrict__ m1, const float* __restrict__ v1,
    const float* __restrict__ g2, const float* __restrict__ b2,
    const float* __restrict__ m2, const float* __restrict__ v2,
    char* __restrict__ w1b, char* __restrict__ w2b,
    float2* __restrict__ ic1, float2* __restrict__ ic2)
{
  int blk = blockIdx.x, lane = threadIdx.x;
  if (blk < 1536) {                       // 2 x 196608 weight elements, 4/thread
    const float* src = (blk < 768) ? w1 : w2;
    char*        dst = (blk < 768) ? w1b : w2b;
    int idx  = ((blk < 768) ? blk : blk - 768) * 64 + lane;
    int base = idx * 4;
    unsigned d = 0;
    #pragma unroll
    for (int j = 0; j < 4; ++j) {
      float v = src[base + j];
      unsigned s = (v < 0.f) ? 0xFFu : (v > 0.f ? 1u : 0u);
      d |= s << (8 * j);
    }
    *(unsigned*)(dst + base) = d;
  } else {
    int i = (blk - 1536) * 64 + lane;     // 1024 BN entries
    if (i < CMID) {
      double inv = (double)g1[i] / sqrt((double)v1[i] + EPSV);
      float2 o; o.x = (float)inv;
      o.y = (float)((double)b1[i] - (double)m1[i] * inv);
      ic1[i] = o;
    } else {
      int j = i - CMID;
      double inv = (double)g2[j] / sqrt((double)v2[j] + EPSV);
      float2 o; o.x = (float)inv;
      o.y = (float)((double)b2[j] - (double)m2[j] * inv);
      ic2[j] = o;
    }
  }
}

// ---------------------------------------------------------------------------
// main: 1568 blocks x 256 thr (4 waves), 64-pixel tile, both layers on MFMA.
// Intermediate sY is BIT-PACKED (ssy[12][64] u64 = 6 KB): L1 epilogue
// accumulates sign nibbles in registers, OR-reduces across g4 via shuffles;
// L2 unpacks 16 bits -> 16 i8 per B-fragment (5 ops/dword).
// LDS 22.5 KB + VGPR<=128 -> 4 blocks/CU (16 waves) vs R8's 2 blocks.
// ---------------------------------------------------------------------------
__global__ __launch_bounds__(256, 4) void bnn_kernel(
    const float* __restrict__ x,
    const char* __restrict__ w1b, const char* __restrict__ w2b,
    const float2* __restrict__ ic1, const float2* __restrict__ ic2,
    float* __restrict__ out)
{
  __shared__ __align__(16) char sBx[64 * 256];   // 16 KB, swizzled
  __shared__ u64 ssy[12][64];                    // 6 KB bit-packed sY

  int t    = threadIdx.x;
  int w    = t >> 6;
  int lane = t & 63;
  int l15  = lane & 15;
  int g4   = lane >> 4;
  int swz  = l15 << 4;

  int px0 = blockIdx.x * 64;           // 1568*64 == 100352 exactly
  int b   = px0 / HW;
  int hw0 = px0 - b * HW;
  const float* xb = x   + (size_t)b * (CIN * HW) + hw0;
  float*       ob = out + (size_t)b * (CIN * HW) + hw0;

  // ---- pack: thread packs px=lane, chans [64w,64w+64) -> i8 {-1,0,1} ----
  {
    const float* xp = xb + lane + (size_t)(w << 6) * HW;
    int rowbase = lane * 256 + (w << 6);
    int pswz    = (lane & 15) << 4;
    #pragma unroll
    for (int j = 0; j < 4; ++j) {      // 4 x b128 (16 chans each)
      unsigned d[4];
      #pragma unroll
      for (int q = 0; q < 4; ++q) {
        unsigned dv = 0;
        #pragma unroll
        for (int bb = 0; bb < 4; ++bb) {
          int c = j * 16 + q * 4 + bb;
          unsigned u = __float_as_uint(xp[(size_t)c * HW]);
          unsigned s = ((u + u) == 0u) ? 0u : (((int)u < 0) ? 0xFFu : 1u);
          dv |= s << (8 * bb);
        }
        d[q] = dv;
      }
      i32x4 v; v.x = (int)d[0]; v.y = (int)d[1]; v.z = (int)d[2]; v.w = (int)d[3];
      *(i32x4*)&sBx[(rowbase + j * 16) ^ pswz] = v;
    }
  }
  __syncthreads();

  // ---- layer 1: wave rows [192w,+192) in 6 chunks of 32; bit epilogue ----
  int wrow = w * 192;
  u64 syb[4][3];                       // [n][word] sign bits, static-indexed
  #pragma unroll
  for (int n = 0; n < 4; ++n)
    #pragma unroll
    for (int j = 0; j < 3; ++j) syb[n][j] = 0ull;

  #pragma unroll
  for (int ch = 0; ch < 6; ++ch) {
    i32x4 acc[2][4];
    #pragma unroll
    for (int m = 0; m < 2; ++m)
      #pragma unroll
      for (int n = 0; n < 4; ++n) acc[m][n] = (i32x4)0;

    #pragma unroll
    for (int ks = 0; ks < 4; ++ks) {
      int k0 = ks * 64 + g4 * 16;
      i32x4 bf[4];
      #pragma unroll
      for (int n = 0; n < 4; ++n)
        bf[n] = *(const i32x4*)&sBx[((n * 16 + l15) * 256 + k0) ^ swz];
      i32x4 af[2];
      #pragma unroll
      for (int m = 0; m < 2; ++m)
        af[m] = *(const i32x4*)&w1b[(size_t)(wrow + ch * 32 + m * 16 + l15) * 256 + k0];
      #pragma unroll
      for (int m = 0; m < 2; ++m)
        #pragma unroll
        for (int n = 0; n < 4; ++n)
          acc[m][n] = __builtin_amdgcn_mfma_i32_16x16x64_i8(
              af[m], bf[n], acc[m][n], 0, 0, 0);
    }

    #pragma unroll
    for (int m = 0; m < 2; ++m) {
      int base = ch * 32 + m * 16;               // compile-time
      int wd   = base >> 6;                      // compile-time 0..2
      int bo   = base & 63;                      // compile-time 0/16/32/48
      int r0   = wrow + base + g4 * 4;
      float2 c0 = ic1[r0], c1 = ic1[r0 + 1], c2 = ic1[r0 + 2], c3 = ic1[r0 + 3];
      #pragma unroll
      for (int n = 0; n < 4; ++n) {
        float y0 = fmaf((float)acc[m][n].x, c0.x, c0.y);
        float y1 = fmaf((float)acc[m][n].y, c1.x, c1.y);
        float y2 = fmaf((float)acc[m][n].z, c2.x, c2.y);
        float y3 = fmaf((float)acc[m][n].w, c3.x, c3.y);
        unsigned nib = (y0 < 0.f ? 1u : 0u) | (y1 < 0.f ? 2u : 0u)
                     | (y2 < 0.f ? 4u : 0u) | (y3 < 0.f ? 8u : 0u);
        syb[n][wd] |= (u64)nib << (bo + g4 * 4);
      }
    }
  }

  // OR-reduce across the 4 g4 groups (lanes +-16, +-32), then store bits
  #pragma unroll
  for (int n = 0; n < 4; ++n)
    #pragma unroll
    for (int j = 0; j < 3; ++j) {
      u64 v = syb[n][j];
      v |= shfl_xor64(v, 16);
      v |= shfl_xor64(v, 32);
      syb[n][j] = v;
    }
  if (g4 == 0) {
    #pragma unroll
    for (int n = 0; n < 4; ++n) ssy[3 * w + 0][n * 16 + l15] = syb[n][0];
  } else if (g4 == 1) {
    #pragma unroll
    for (int n = 0; n < 4; ++n) ssy[3 * w + 1][n * 16 + l15] = syb[n][1];
  } else if (g4 == 2) {
    #pragma unroll
    for (int n = 0; n < 4; ++n) ssy[3 * w + 2][n * 16 + l15] = syb[n][2];
  }
  __syncthreads();

  // ---- layer 2: wave rows [64w,+64), K=768, B-frags unpacked from bits ----
  {
    int rbase = w << 6;
    i32x4 acc[4][4];
    #pragma unroll
    for (int m = 0; m < 4; ++m)
      #pragma unroll
      for (int n = 0; n < 4; ++n) acc[m][n] = (i32x4)0;

    #pragma unroll
    for (int ks = 0; ks < 12; ++ks) {
      int k0 = ks * 64 + g4 * 16;
      i32x4 bf[4];
      #pragma unroll
      for (int n = 0; n < 4; ++n) {
        u64 wv = ssy[ks][n * 16 + l15];
        unsigned bits = (unsigned)(wv >> (g4 * 16)) & 0xFFFFu;
        bf[n] = unpack16(bits);
      }
      i32x4 af[4];
      #pragma unroll
      for (int m = 0; m < 4; ++m)
        af[m] = *(const i32x4*)&w2b[(size_t)(rbase + m * 16 + l15) * 768 + k0];
      #pragma unroll
      for (int m = 0; m < 4; ++m)
        #pragma unroll
        for (int n = 0; n < 4; ++n)
          acc[m][n] = __builtin_amdgcn_mfma_i32_16x16x64_i8(
              af[m], bf[n], acc[m][n], 0, 0, 0);
    }

    // epilogue: BN + residual + store
    #pragma unroll
    for (int m = 0; m < 4; ++m) {
      int r0 = rbase + m * 16 + g4 * 4;
      float2 c0 = ic2[r0], c1 = ic2[r0 + 1], c2 = ic2[r0 + 2], c3 = ic2[r0 + 3];
      #pragma unroll
      for (int n = 0; n < 4; ++n) {
        int pxo = n * 16 + l15;
        const float* xq = xb + pxo;
        float*       oq = ob + pxo;
        size_t o0 = (size_t)r0 * HW;
        oq[o0]          = fmaf((float)acc[m][n].x, c0.x, c0.y) + xq[o0];
        oq[o0 + HW]     = fmaf((float)acc[m][n].y, c1.x, c1.y) + xq[o0 + HW];
        oq[o0 + 2 * HW] = fmaf((float)acc[m][n].z, c2.x, c2.y) + xq[o0 + 2 * HW];
        oq[o0 + 3 * HW] = fmaf((float)acc[m][n].w, c3.x, c3.y) + xq[o0 + 3 * HW];
      }
    }
  }
}

extern "C" void kernel_launch(void* const* d_in, const int* in_sizes, int n_in,
                              void* d_out, int out_size, void* d_ws, size_t ws_size,
                              hipStream_t stream) {
  const float* x  = (const float*)d_in[0];
  const float* w1 = (const float*)d_in[1];
  const float* w2 = (const float*)d_in[2];
  const float* g1 = (const float*)d_in[3];
  const float* b1 = (const float*)d_in[4];
  const float* m1 = (const float*)d_in[5];
  const float* v1 = (const float*)d_in[6];
  const float* g2 = (const float*)d_in[7];
  const float* b2 = (const float*)d_in[8];
  const float* m2 = (const float*)d_in[9];
  const float* v2 = (const float*)d_in[10];
  float* out = (float*)d_out;

  char*   w1b = (char*)d_ws;               // 196608 B
  char*   w2b = w1b + 196608;              // 196608 B
  float2* ic1 = (float2*)(w2b + 196608);   // 768 * 8 B
  float2* ic2 = ic1 + CMID;                // 256 * 8 B

  prep_kernel<<<1552, 64, 0, stream>>>(w1, w2, g1, b1, m1, v1,
                                       g2, b2, m2, v2, w1b, w2b, ic1, ic2);
  bnn_kernel<<<1568, 256, 0, stream>>>(x, w1b, w2b, ic1, ic2, out);
}

// Round 10
// 134.642 us; speedup vs baseline: 1.3024x; 1.3024x over previous
//
#include <hip/hip_runtime.h>

typedef unsigned long long u64;

#define HW    3136      // 56*56
#define CIN   256
#define CMID  768
#define EPSV  1e-5

// ---------------------------------------------------------------------------
// prep: pack weight sign bits (bit=1 <=> w<0); layer-1 BN folded to integer
// threshold t1[o] (sign(y1bn)<0 <=> 2p > t1, p = popc mismatches);
// layer-2 BN folded to float2 (A2,B2): y2 = p*A2 + B2.
// ---------------------------------------------------------------------------
__global__ __launch_bounds__(64) void prep_kernel(
    const float* __restrict__ w1, const float* __restrict__ w2,
    const float* __restrict__ g1, const float* __restrict__ b1,
    const float* __restrict__ m1, const float* __restrict__ v1,
    const float* __restrict__ g2, const float* __restrict__ b2,
    const float* __restrict__ m2, const float* __restrict__ v2,
    u64* __restrict__ pw1, u64* __restrict__ pw2,
    int* __restrict__ t1, float2* __restrict__ ab2)
{
  int blk  = blockIdx.x;
  int lane = threadIdx.x;
  if (blk < 3072) {                       // w1: 768 rows x 4 words
    int o = blk >> 2, seg = blk & 3;
    u64 msk = __ballot(w1[o * CIN + (seg << 6) + lane] < 0.0f);
    if (lane == 0) pw1[blk] = msk;
  } else if (blk < 6144) {                // w2: 256 rows x 12 words
    int i = blk - 3072;
    int o = i / 12, seg = i - o * 12;
    u64 msk = __ballot(w2[o * CMID + (seg << 6) + lane] < 0.0f);
    if (lane == 0) pw2[i] = msk;
  } else {                                // BN constants
    int i = ((blk - 6144) << 6) + lane;
    if (i < CMID) {
      double inv = (double)g1[i] / sqrt((double)v1[i] + EPSV);
      double c   = (double)b1[i] - (double)m1[i] * inv;
      // y1bn < 0  <=>  2p > 256 + c/inv   (inv > 0 always)
      t1[i] = (int)floor(256.0 + c / inv);
    } else if (i < CMID + CIN) {
      int j = i - CMID;
      double inv = (double)g2[j] / sqrt((double)v2[j] + EPSV);
      float2 o2;
      o2.x = (float)(-2.0 * inv);
      o2.y = (float)(768.0 * inv + (double)b2[j] - (double)m2[j] * inv);
      ab2[j] = o2;
    }
  }
}

// ---------------------------------------------------------------------------
// main: 1568 blocks x 256 thr (4 waves), 64-pixel tile.  (R6 structure)
// L1: wave w's lane l holds W1 rows o = 192w + 64k + l (k=0..2) in VGPRs;
//     px loop reads packed sx via 2x ds_read_b128 (2-deep prefetch),
//     __ballot(2p > t1) IS packed sy word 3w+k.
// L2: lane = pixel, wave w rows [64w,+64); W2 + BN via readfirstlane-uniform
//     s_load stream; residual x prefetched in 16-row groups, 1 group ahead.
// ---------------------------------------------------------------------------
__global__ __launch_bounds__(256, 6) void bnn_kernel(
    const float* __restrict__ x,
    const u64* __restrict__ pw1, const u64* __restrict__ pw2,
    const int* __restrict__ t1g, const float2* __restrict__ ab2g,
    float* __restrict__ out)
{
  __shared__ __align__(16) u64 ssx[64][6];  // 3 KB  [px][word], b128-readable
  __shared__ __align__(16) u64 szx[64][6];  // 3 KB  zero masks (rarely hot)
  __shared__ u64 ssy[64][13];               // 6.5 KB sy exchange
  __shared__ u64 szf[4];                    // has-zero pixel bitmasks

  int t    = threadIdx.x;
  int w    = t >> 6;
  int lane = t & 63;
  int px0  = blockIdx.x * 64;    // 1568*64 == 100352 exactly

  // ---- W1 rows + thresholds into registers (row o = 192w + 64k + lane) ----
  u64 w1r[3][4]; int t1r[3];
  #pragma unroll
  for (int k = 0; k < 3; ++k) {
    int o = w * 192 + (k << 6) + lane;
    ulonglong2 a  = *(const ulonglong2*)&pw1[(size_t)(o << 2)];
    ulonglong2 bq = *(const ulonglong2*)&pw1[(size_t)(o << 2) + 2];
    w1r[k][0] = a.x; w1r[k][1] = a.y; w1r[k][2] = bq.x; w1r[k][3] = bq.y;
    t1r[k] = t1g[o];
  }

  // ---- pack: thread -> pixel=lane, channel group w ([64w,64w+64)) ----
  {
    int px = px0 + lane;
    int pb = px / HW, phw = px - pb * HW;
    const float* xp = x + (size_t)pb * (CIN * HW) + phw + (size_t)(w << 6) * HW;
    u64 s = 0;
    unsigned mn = ~0u;
    #pragma unroll 8
    for (int c = 0; c < 64; ++c) {
      unsigned u = __float_as_uint(xp[(size_t)c * HW]);
      s |= (u64)(u >> 31) << c;
      unsigned m = u + u;                 // clears sign; 0 <=> x==+-0.0
      mn = mn < m ? mn : m;
    }
    ssx[lane][w] = s;
    u64 z = 0;
    if (__builtin_expect(mn == 0u, 0)) {  // rare exact-zero rebuild
      for (int c = 0; c < 64; ++c) {
        unsigned u = __float_as_uint(xp[(size_t)c * HW]);
        z |= (u64)((u + u) == 0u ? 1u : 0u) << c;
      }
    }
    szx[lane][w] = z;
    u64 zb = __ballot(z != 0ull);         // bit l = pixel l has a zero
    if (lane == 0) szf[w] = zb;
  }
  __syncthreads();

  u64 zm = szf[0] | szf[1] | szf[2] | szf[3];

  // ---- layer 1: pixel loop, ballot-transpose, 2-deep sx prefetch ----
  u64 c0 = 0, c1 = 0, c2 = 0;
  ulonglong2 xaN = *(const ulonglong2*)&ssx[0][0];
  ulonglong2 xbN = *(const ulonglong2*)&ssx[0][2];
  #pragma unroll 4
  for (int q = 0; q < 64; ++q) {
    ulonglong2 xa = xaN, xb = xbN;
    if (q < 63) {
      xaN = *(const ulonglong2*)&ssx[q + 1][0];
      xbN = *(const ulonglong2*)&ssx[q + 1][2];
    }
    int pv0, pv1, pv2;
    {
      int pk;
      pk = __popcll(w1r[0][0] ^ xa.x) + __popcll(w1r[0][1] ^ xa.y)
         + __popcll(w1r[0][2] ^ xb.x) + __popcll(w1r[0][3] ^ xb.y);
      pv0 = pk + pk;
      pk = __popcll(w1r[1][0] ^ xa.x) + __popcll(w1r[1][1] ^ xa.y)
         + __popcll(w1r[1][2] ^ xb.x) + __popcll(w1r[1][3] ^ xb.y);
      pv1 = pk + pk;
      pk = __popcll(w1r[2][0] ^ xa.x) + __popcll(w1r[2][1] ^ xa.y)
         + __popcll(w1r[2][2] ^ xb.x) + __popcll(w1r[2][3] ^ xb.y);
      pv2 = pk + pk;
    }
    if (__builtin_expect((int)((zm >> q) & 1ull), 0)) {
      // exact: y1 = 256 - 2p - K0 + 2dz ; bit <=> (2p + K0 - 2dz) > t1
      ulonglong2 za = *(const ulonglong2*)&szx[q][0];
      ulonglong2 zb = *(const ulonglong2*)&szx[q][2];
      int K0 = __popcll(za.x) + __popcll(za.y) + __popcll(zb.x) + __popcll(zb.y);
      #pragma unroll
      for (int k = 0; k < 3; ++k) {
        int dz = __popcll((w1r[k][0] ^ xa.x) & za.x)
               + __popcll((w1r[k][1] ^ xa.y) & za.y)
               + __popcll((w1r[k][2] ^ xb.x) & zb.x)
               + __popcll((w1r[k][3] ^ xb.y) & zb.y);
        int adj = K0 - dz - dz;
        if (k == 0) pv0 += adj; else if (k == 1) pv1 += adj; else pv2 += adj;
      }
    }
    u64 b0 = __ballot(pv0 > t1r[0]);
    u64 b1 = __ballot(pv1 > t1r[1]);
    u64 b2 = __ballot(pv2 > t1r[2]);
    if (lane == q) { c0 = b0; c1 = b1; c2 = b2; }
  }

  ssy[lane][3 * w + 0] = c0;
  ssy[lane][3 * w + 1] = c1;
  ssy[lane][3 * w + 2] = c2;
  __syncthreads();

  // ---- layer 2: lane = pixel, wave w rows [64w,+64); W2 via s_load ----
  u64 sy[12];
  #pragma unroll
  for (int j = 0; j < 12; ++j) sy[j] = ssy[lane][j];

  int px = px0 + lane;
  int pb = px / HW, phw = px - pb * HW;
  const float* xr = x   + (size_t)pb * (CIN * HW) + phw;
  float*       op = out + (size_t)pb * (CIN * HW) + phw;
  int ob = w << 6;

#define LOADG(RX, G)                                                          \
  _Pragma("unroll") for (int i = 0; i < 16; ++i)                              \
    RX[i] = xr[(size_t)(ob + (G) * 16 + i) * HW];

#define COMPG(RX, G)                                                          \
  _Pragma("unroll") for (int j = 0; j < 16; ++j) {                            \
    int o  = ob + (G) * 16 + j;                                               \
    int ou = __builtin_amdgcn_readfirstlane(o);                               \
    const u64* wr = pw2 + (size_t)ou * 12;                                    \
    float2 ab = ab2g[ou];                                                     \
    int pa = __popcll(wr[0] ^ sy[0])  + __popcll(wr[1]  ^ sy[1])              \
           + __popcll(wr[2] ^ sy[2])  + __popcll(wr[3]  ^ sy[3])              \
           + __popcll(wr[4] ^ sy[4])  + __popcll(wr[5]  ^ sy[5]);             \
    int pb2 = __popcll(wr[6] ^ sy[6])  + __popcll(wr[7]  ^ sy[7])             \
            + __popcll(wr[8] ^ sy[8])  + __popcll(wr[9]  ^ sy[9])             \
            + __popcll(wr[10] ^ sy[10]) + __popcll(wr[11] ^ sy[11]);          \
    float y = fmaf((float)(pa + pb2), ab.x, ab.y);                            \
    op[(size_t)o * HW] = y + RX[j];                                           \
  }

  float rxA[16], rxB[16];
  LOADG(rxA, 0);
  LOADG(rxB, 1);
  COMPG(rxA, 0);
  LOADG(rxA, 2);
  COMPG(rxB, 1);
  LOADG(rxB, 3);
  COMPG(rxA, 2);
  COMPG(rxB, 3);
#undef LOADG
#undef COMPG
}

extern "C" void kernel_launch(void* const* d_in, const int* in_sizes, int n_in,
                              void* d_out, int out_size, void* d_ws, size_t ws_size,
                              hipStream_t stream) {
  const float* x  = (const float*)d_in[0];
  const float* w1 = (const float*)d_in[1];
  const float* w2 = (const float*)d_in[2];
  const float* g1 = (const float*)d_in[3];
  const float* b1 = (const float*)d_in[4];
  const float* m1 = (const float*)d_in[5];
  const float* v1 = (const float*)d_in[6];
  const float* g2 = (const float*)d_in[7];
  const float* b2 = (const float*)d_in[8];
  const float* m2 = (const float*)d_in[9];
  const float* v2 = (const float*)d_in[10];
  float* out = (float*)d_out;

  u64*    pw1 = (u64*)d_ws;
  u64*    pw2 = pw1 + 3072;
  int*    t1  = (int*)(pw2 + 3072);
  float2* ab2 = (float2*)(t1 + CMID);

  prep_kernel<<<6160, 64, 0, stream>>>(w1, w2, g1, b1, m1, v1,
                                       g2, b2, m2, v2, pw1, pw2, t1, ab2);
  bnn_kernel<<<1568, 256, 0, stream>>>(x, pw1, pw2, t1, ab2, out);
}

// Round 11
// 128.639 us; speedup vs baseline: 1.3632x; 1.0467x over previous
//
#include <hip/hip_runtime.h>

typedef unsigned long long u64;

#define HW    3136      // 56*56
#define CIN   256
#define CMID  768
#define EPSV  1e-5

// ---------------------------------------------------------------------------
// prep: pack weight sign bits (bit=1 <=> w<0); layer-1 BN folded to integer
// threshold t1[o] (sign(y1bn)<0 <=> 2p > t1, p = popc mismatches);
// layer-2 BN folded to float2 (A2,B2): y2 = p*A2 + B2.
// ---------------------------------------------------------------------------
__global__ __launch_bounds__(64) void prep_kernel(
    const float* __restrict__ w1, const float* __restrict__ w2,
    const float* __restrict__ g1, const float* __restrict__ b1,
    const float* __restrict__ m1, const float* __restrict__ v1,
    const float* __restrict__ g2, const float* __restrict__ b2,
    const float* __restrict__ m2, const float* __restrict__ v2,
    u64* __restrict__ pw1, u64* __restrict__ pw2,
    int* __restrict__ t1, float2* __restrict__ ab2)
{
  int blk  = blockIdx.x;
  int lane = threadIdx.x;
  if (blk < 3072) {                       // w1: 768 rows x 4 words
    int o = blk >> 2, seg = blk & 3;
    u64 msk = __ballot(w1[o * CIN + (seg << 6) + lane] < 0.0f);
    if (lane == 0) pw1[blk] = msk;
  } else if (blk < 6144) {                // w2: 256 rows x 12 words
    int i = blk - 3072;
    int o = i / 12, seg = i - o * 12;
    u64 msk = __ballot(w2[o * CMID + (seg << 6) + lane] < 0.0f);
    if (lane == 0) pw2[i] = msk;
  } else {                                // BN constants
    int i = ((blk - 6144) << 6) + lane;
    if (i < CMID) {
      double inv = (double)g1[i] / sqrt((double)v1[i] + EPSV);
      double c   = (double)b1[i] - (double)m1[i] * inv;
      // y1bn < 0  <=>  2p > 256 + c/inv   (inv > 0 always)
      t1[i] = (int)floor(256.0 + c / inv);
    } else if (i < CMID + CIN) {
      int j = i - CMID;
      double inv = (double)g2[j] / sqrt((double)v2[j] + EPSV);
      float2 o2;
      o2.x = (float)(-2.0 * inv);
      o2.y = (float)(768.0 * inv + (double)b2[j] - (double)m2[j] * inv);
      ab2[j] = o2;
    }
  }
}

// ---------------------------------------------------------------------------
// main: 1792 blocks x 256 thr (4 waves), 56-pixel tile -> EXACTLY 7 blocks/CU
// (1792 = 7*256): no refill/drain tail, all CUs finish together.
// L1: wave w's lane l holds W1 rows o = 192w + 64k + l (k=0..2) in VGPRs;
//     56-pixel loop, broadcast-read packed sx from ssx[4][64] (conflict-free),
//     __ballot(2p > t1) IS packed sy word 3w+k of that pixel.
// L2: lane = pixel (lanes 56-63 masked), wave w rows [64w,+64); W2 + BN via
//     readfirstlane-uniform s_load stream.
// ---------------------------------------------------------------------------
__global__ __launch_bounds__(256, 7) void bnn_kernel(
    const float* __restrict__ x,
    const u64* __restrict__ pw1, const u64* __restrict__ pw2,
    const int* __restrict__ t1g, const float2* __restrict__ ab2g,
    float* __restrict__ out)
{
  __shared__ u64 ssx[4][64];     // 2 KB  packed sign(x), [ch-group][pixel]
  __shared__ u64 szx[4][64];     // 2 KB  zero masks
  __shared__ u64 ssy[64][13];    // 6.5 KB sy exchange (pad 13: benign banks)
  __shared__ u64 szf[4];         // has-zero pixel bitmasks

  int t    = threadIdx.x;
  int w    = t >> 6;
  int lane = t & 63;
  int px0  = blockIdx.x * 56;    // 1792*56 == 100352 exactly; image-aligned

  // ---- W1 rows + thresholds into registers (row o = 192w + 64k + lane) ----
  u64 w1r[3][4]; int t1r[3];
  #pragma unroll
  for (int k = 0; k < 3; ++k) {
    int o = w * 192 + (k << 6) + lane;
    ulonglong2 a  = *(const ulonglong2*)&pw1[(size_t)(o << 2)];
    ulonglong2 bq = *(const ulonglong2*)&pw1[(size_t)(o << 2) + 2];
    w1r[k][0] = a.x; w1r[k][1] = a.y; w1r[k][2] = bq.x; w1r[k][3] = bq.y;
    t1r[k] = t1g[o];
  }

  // ---- pack: thread -> pixel=lane (<56), channel group w ([64w,64w+64)) ----
  if (lane < 56) {
    int px = px0 + lane;
    int pb = px / HW, phw = px - pb * HW;
    const float* xp = x + (size_t)pb * (CIN * HW) + phw + (size_t)(w << 6) * HW;
    u64 s = 0;
    unsigned mn = ~0u;
    #pragma unroll 8
    for (int c = 0; c < 64; ++c) {
      unsigned u = __float_as_uint(xp[(size_t)c * HW]);
      s |= (u64)(u >> 31) << c;
      unsigned m = u + u;                 // clears sign; 0 <=> x==+-0.0
      mn = mn < m ? mn : m;
    }
    u64 z = 0;
    if (__builtin_expect(mn == 0u, 0)) {  // rare exact-zero rebuild
      for (int c = 0; c < 64; ++c) {
        unsigned u = __float_as_uint(xp[(size_t)c * HW]);
        z |= (u64)((u + u) == 0u ? 1u : 0u) << c;
      }
    }
    ssx[w][lane] = s;
    szx[w][lane] = z;
    u64 zb = __ballot(z != 0ull);         // bit l = pixel l has a zero
    if (lane == 0) szf[w] = zb;
  }
  __syncthreads();

  u64 zm = szf[0] | szf[1] | szf[2] | szf[3];

  // ---- layer 1: 56-pixel loop, ballot-transpose ----
  u64 c0 = 0, c1 = 0, c2 = 0;
  #pragma unroll 4
  for (int q = 0; q < 56; ++q) {
    u64 x0 = ssx[0][q], x1 = ssx[1][q], x2 = ssx[2][q], x3 = ssx[3][q];
    int pv0, pv1, pv2;
    {
      int pk;
      pk = __popcll(w1r[0][0] ^ x0) + __popcll(w1r[0][1] ^ x1)
         + __popcll(w1r[0][2] ^ x2) + __popcll(w1r[0][3] ^ x3);
      pv0 = pk + pk;
      pk = __popcll(w1r[1][0] ^ x0) + __popcll(w1r[1][1] ^ x1)
         + __popcll(w1r[1][2] ^ x2) + __popcll(w1r[1][3] ^ x3);
      pv1 = pk + pk;
      pk = __popcll(w1r[2][0] ^ x0) + __popcll(w1r[2][1] ^ x1)
         + __popcll(w1r[2][2] ^ x2) + __popcll(w1r[2][3] ^ x3);
      pv2 = pk + pk;
    }
    if (__builtin_expect((int)((zm >> q) & 1ull), 0)) {
      // exact: y1 = 256 - 2p - K0 + 2dz ; bit <=> (2p + K0 - 2dz) > t1
      u64 z0 = szx[0][q], z1 = szx[1][q], z2 = szx[2][q], z3 = szx[3][q];
      int K0 = __popcll(z0) + __popcll(z1) + __popcll(z2) + __popcll(z3);
      #pragma unroll
      for (int k = 0; k < 3; ++k) {
        int dz = __popcll((w1r[k][0] ^ x0) & z0)
               + __popcll((w1r[k][1] ^ x1) & z1)
               + __popcll((w1r[k][2] ^ x2) & z2)
               + __popcll((w1r[k][3] ^ x3) & z3);
        int adj = K0 - dz - dz;
        if (k == 0) pv0 += adj; else if (k == 1) pv1 += adj; else pv2 += adj;
      }
    }
    u64 b0 = __ballot(pv0 > t1r[0]);
    u64 b1 = __ballot(pv1 > t1r[1]);
    u64 b2 = __ballot(pv2 > t1r[2]);
    if (lane == q) { c0 = b0; c1 = b1; c2 = b2; }
  }

  ssy[lane][3 * w + 0] = c0;
  ssy[lane][3 * w + 1] = c1;
  ssy[lane][3 * w + 2] = c2;
  __syncthreads();

  // ---- layer 2: lane = pixel (<56), wave w rows [64w,+64); W2 via s_load ----
  u64 sy[12];
  #pragma unroll
  for (int j = 0; j < 12; ++j) sy[j] = ssy[lane][j];

  bool act = lane < 56;
  int px = px0 + (act ? lane : 0);        // clamp inactive lanes in-bounds
  int pb = px / HW, phw = px - pb * HW;
  const float* xr = x   + (size_t)pb * (CIN * HW) + phw;
  float*       op = out + (size_t)pb * (CIN * HW) + phw;

  int ob = w << 6;
  #pragma unroll 2
  for (int j = 0; j < 64; ++j) {
    int o  = ob + j;
    int ou = __builtin_amdgcn_readfirstlane(o);        // provably uniform
    const u64* wr = pw2 + (size_t)ou * 12;             // -> s_load stream
    float2 ab = ab2g[ou];                              // -> s_load
    int pa = __popcll(wr[0] ^ sy[0])  + __popcll(wr[1]  ^ sy[1])
           + __popcll(wr[2] ^ sy[2])  + __popcll(wr[3]  ^ sy[3])
           + __popcll(wr[4] ^ sy[4])  + __popcll(wr[5]  ^ sy[5]);
    int pb2 = __popcll(wr[6] ^ sy[6])  + __popcll(wr[7]  ^ sy[7])
            + __popcll(wr[8] ^ sy[8])  + __popcll(wr[9]  ^ sy[9])
            + __popcll(wr[10] ^ sy[10]) + __popcll(wr[11] ^ sy[11]);
    float y = fmaf((float)(pa + pb2), ab.x, ab.y);
    if (act) op[(size_t)o * HW] = y + xr[(size_t)o * HW];
  }
}

extern "C" void kernel_launch(void* const* d_in, const int* in_sizes, int n_in,
                              void* d_out, int out_size, void* d_ws, size_t ws_size,
                              hipStream_t stream) {
  const float* x  = (const float*)d_in[0];
  const float* w1 = (const float*)d_in[1];
  const float* w2 = (const float*)d_in[2];
  const float* g1 = (const float*)d_in[3];
  const float* b1 = (const float*)d_in[4];
  const float* m1 = (const float*)d_in[5];
  const float* v1 = (const float*)d_in[6];
  const float* g2 = (const float*)d_in[7];
  const float* b2 = (const float*)d_in[8];
  const float* m2 = (const float*)d_in[9];
  const float* v2 = (const float*)d_in[10];
  float* out = (float*)d_out;

  u64*    pw1 = (u64*)d_ws;
  u64*    pw2 = pw1 + 3072;
  int*    t1  = (int*)(pw2 + 3072);
  float2* ab2 = (float2*)(t1 + CMID);

  prep_kernel<<<6160, 64, 0, stream>>>(w1, w2, g1, b1, m1, v1,
                                       g2, b2, m2, v2, pw1, pw2, t1, ab2);
  bnn_kernel<<<1792, 256, 0, stream>>>(x, pw1, pw2, t1, ab2, out);
}